// Round 8
// baseline (441.021 us; speedup 1.0000x reference)
//
#include <hip/hip_runtime.h>
#include <cstddef>

// Problem shapes (fixed by reference)
#define NBH  1024   // B*H
#define Mm   196
#define Dd   128
#define MIDe 64
#define DVv  128
#define WQLD 136    // WqT row length in shorts (128 + 8 pad -> 272 B rows)

typedef __attribute__((ext_vector_type(8))) short bf16x8;  // 8 bf16 in 4 VGPRs
typedef __attribute__((ext_vector_type(4))) float f32x4;   // MFMA C/D frag

__device__ __forceinline__ short f2bf(float x) {           // fp32 -> bf16 RNE
    union { float f; unsigned u; } v; v.f = x;
    return (short)((v.u + 0x7FFFu + ((v.u >> 16) & 1u)) >> 16);
}

// async 16B global->LDS DMA: no data VGPRs, tracked by vmcnt.
// LDS dest is wave-uniform base + lane*16 (HW); global src is per-lane.
__device__ __forceinline__ void gl_lds16(const void* g, void* l) {
    __builtin_amdgcn_global_load_lds(
        (const __attribute__((address_space(1))) unsigned int*)g,
        (__attribute__((address_space(3))) unsigned int*)l, 16, 0, 0);
}

// Round-8 architecture: rounds 3-7 showed per-wave register bursts are a
// dead end (budget 128 -> 50-60 MB spills; budget 256 -> allocator settles
// at ~100-120 regs and serializes loads into small vmcnt chunks; waves sit
// idle with ~0 bytes outstanding -> 1.2 TB/s, 88 us regardless of MLP).
// Fix: global_load_lds staging (zero data regs, compiler can't chunk it):
//  - key tile double-buffered in LDS, stored TRANSPOSED in 16B cells
//    [d4][row] via per-lane src addressing -> frag ds_read_b128 are
//    consecutive-slot (conflict-free); stage = 2 instr/wave/tile.
//  - all 4 waves compute each tile redundantly (16 MFMA -> cheap), which
//    deletes the cross-wave softmax merge; each wave owns 32 v2 columns
//    (4 float2 regs/tile, double-buffered).
//  - in-loop sync: counted s_waitcnt vmcnt(4) + raw s_barrier (never drain
//    the just-issued next-tile stage; __syncthreads would).
// Demand ~100 VGPR -> launch_bounds(256,4); LDS ~35.5 KB -> 4 blocks/CU,
// 16 waves/CU, ~16 KB in flight per block continuously.
__global__ __launch_bounds__(256, 4)
void scatt_fused(const float* __restrict__ query,
                 const float* __restrict__ key,
                 const float* __restrict__ att_mask,
                 const float* __restrict__ value1,
                 const float* __restrict__ value2,
                 const float* __restrict__ W_basic,
                 const float* __restrict__ b_basic,
                 const float* __restrict__ W_spatial,
                 const float* __restrict__ b_spatial,
                 const float* __restrict__ W_channel,
                 const float* __restrict__ b_channel,
                 float* __restrict__ out)
{
    __shared__ float4 kb[2][32][16];    // 16 KB: key tile dbuf, cell [d4][row]
    __shared__ short  wqT[MIDe][WQLD];  // 17.4 KB bf16 Wq^T[e][d]
    __shared__ float  qS[Dd];
    __shared__ float  maskS[Mm];
    __shared__ float  poolS[MIDe];

    const int t    = threadIdx.x;
    const int lane = t & 63;
    const int w    = t >> 6;            // wave id 0..3
    const int ln15 = lane & 15;
    const int q4   = lane >> 4;         // quad id 0..3
    const int bh   = blockIdx.x;
    const int b    = bh >> 3;

    const char*  keyC  = (const char*)(key + (size_t)bh * Mm * Dd);
    const float* val2B = value2   + (size_t)bh * Mm * DVv;
    const float* qB    = query    + (size_t)bh * Dd;
    const float* maskB = att_mask + (size_t)b  * Mm;

    // Staging source offsets (transpose done on the per-lane SOURCE side):
    // dest 16B-cell index = w*128 + j*64 + lane; d4 = cell>>4, row = cell&15;
    // src byte within tile = row*512 + d4*16. Tile 12 clamps row to 3
    // (rows 196..207 read row-195 data; their logits are masked -> p==0).
    int so[2], soT[2];
#pragma unroll
    for (int j = 0; j < 2; ++j) {
        const int cell = w * 128 + j * 64 + lane;
        const int d4 = cell >> 4, row = cell & 15;
        so[j]  = row * 512 + d4 * 16;
        soT[j] = (row < 4 ? row : 3) * 512 + d4 * 16;
    }
    const int colOff = w * 32 + 2 * ln15;   // v2 column pair this lane owns

    // ---- issue stage(0) + v2(0) immediately (fly under the prologue)
    gl_lds16(keyC + so[0], (char*)kb + w * 2048);
    gl_lds16(keyC + so[1], (char*)kb + w * 2048 + 1024);
    float2 vv[2][4];
#pragma unroll
    for (int rr = 0; rr < 4; ++rr)
        vv[0][rr] = *(const float2*)(val2B + (size_t)(q4 * 4 + rr) * DVv + colOff);

    // ---- Prologue: stage q + mask; build WqT cooperatively ----
    if (t < 32) ((float4*)qS)[t] = ((const float4*)qB)[t];
    for (int i = t; i < Mm; i += 256) maskS[i] = maskB[i];
    __syncthreads();
    {
        const int e0 = lane;            // e column this thread fills
        const int d0 = w * 32;
#pragma unroll
        for (int c = 0; c < 4; ++c) {
            short pk[8];
#pragma unroll
            for (int j = 0; j < 8; ++j) {
                const int d = d0 + c * 8 + j;
                pk[j] = f2bf(qS[d] * W_basic[d * MIDe + e0]);
            }
            *(bf16x8*)&wqT[e0][d0 + c * 8] = *(bf16x8*)pk;
        }
    }
    __syncthreads();   // drains vmcnt too -> stage(0)/v2(0) complete here

    float bbv[4], wspv[4];
#pragma unroll
    for (int nt = 0; nt < 4; ++nt) {
        bbv[nt]  = b_basic[nt * 16 + ln15];
        wspv[nt] = W_spatial[nt * 16 + ln15];
    }
    const float bsp = b_spatial[0];

    float poolAcc[4] = {0.f, 0.f, 0.f, 0.f};
    float m_run = -3.0e38f, l_run = 0.f;
    float2 av = make_float2(0.f, 0.f);

    // ---- Main loop: 13 tiles, all waves in lockstep (redundant compute) ----
#pragma unroll
    for (int mt = 0; mt < 13; ++mt) {
        // wait: my stage(mt) done (leaves stage(mt+1)-to-be + v2 in flight)
        asm volatile("s_waitcnt vmcnt(4)" ::: "memory");
        __builtin_amdgcn_s_barrier();        // all waves' stage(mt) visible
        __builtin_amdgcn_sched_barrier(0);   // nothing moves above this
        if (mt < 12) {
            char* db = (char*)kb + ((mt + 1) & 1) * 8192;
            const char* sb = keyC + (size_t)(mt + 1) * 8192;
            if (mt + 1 < 12) {
                gl_lds16(sb + so[0], db + w * 2048);
                gl_lds16(sb + so[1], db + w * 2048 + 1024);
            } else {
                gl_lds16(sb + soT[0], db + w * 2048);
                gl_lds16(sb + soT[1], db + w * 2048 + 1024);
            }
            __builtin_amdgcn_sched_barrier(0);  // keep stage ahead of v2 in queue
#pragma unroll
            for (int rr = 0; rr < 4; ++rr) {
                int vrow = (mt + 1) * 16 + q4 * 4 + rr;
                if (mt + 1 == 12) vrow = vrow < Mm ? vrow : (Mm - 1);
                vv[(mt + 1) & 1][rr] =
                    *(const float2*)(val2B + (size_t)vrow * DVv + colOff);
            }
        }

        // ---- compute tile mt from kb[mt&1] (every wave, redundant) ----
        const char* kbB = (const char*)kb + (mt & 1) * 8192;
        f32x4 acc[4] = {f32x4{0,0,0,0}, f32x4{0,0,0,0},
                        f32x4{0,0,0,0}, f32x4{0,0,0,0}};
#pragma unroll
        for (int ks = 0; ks < 4; ++ks) {
            const int d4 = ks * 8 + q4 * 2;
            const float4 f0 = *(const float4*)(kbB + d4 * 256 + ln15 * 16);
            const float4 f1 = *(const float4*)(kbB + d4 * 256 + 256 + ln15 * 16);
            const bf16x8 af = { f2bf(f0.x), f2bf(f0.y), f2bf(f0.z), f2bf(f0.w),
                                f2bf(f1.x), f2bf(f1.y), f2bf(f1.z), f2bf(f1.w) };
#pragma unroll
            for (int nt = 0; nt < 4; ++nt) {
                const bf16x8 bk =
                    *(const bf16x8*)&wqT[nt * 16 + ln15][ks * 32 + q4 * 8];
                acc[nt] = __builtin_amdgcn_mfma_f32_16x16x32_bf16(
                              af, bk, acc[nt], 0, 0, 0);
            }
        }

        // logits: C/D col = ln15 (e), row = q4*4 + rr; lane's rows == its v2 rows
        float sR[4];
#pragma unroll
        for (int rr = 0; rr < 4; ++rr) {
            const int m = mt * 16 + q4 * 4 + rr;
            const bool valid = (mt < 12) || (m < Mm);
            const float msk = valid ? maskS[m < Mm ? m : (Mm - 1)] : 0.f;
            float srow = 0.f;
#pragma unroll
            for (int nt = 0; nt < 4; ++nt) {
                float hv = acc[nt][rr] + bbv[nt];
                hv = hv > 0.f ? hv : 0.f;                 // relu
                poolAcc[nt] = fmaf(hv, msk, poolAcc[nt]); // masked pool partial
                srow = fmaf(hv, wspv[nt], srow);          // h[m,:].W_spatial
            }
            srow += __shfl_xor(srow, 1, 64);
            srow += __shfl_xor(srow, 2, 64);
            srow += __shfl_xor(srow, 4, 64);
            srow += __shfl_xor(srow, 8, 64);
            sR[rr] = valid ? (msk == 0.f ? -1.0e9f : srow + bsp) : -3.0e38f;
        }
        float tm = fmaxf(fmaxf(sR[0], sR[1]), fmaxf(sR[2], sR[3]));
        tm = fmaxf(tm, __shfl_xor(tm, 16, 64));
        tm = fmaxf(tm, __shfl_xor(tm, 32, 64));

        const float newm = fmaxf(m_run, tm);   // identical across waves
        const float sc = __expf(m_run - newm);
        m_run = newm;
        l_run *= sc; av.x *= sc; av.y *= sc;
#pragma unroll
        for (int rr = 0; rr < 4; ++rr) {
            const float p = __expf(sR[rr] - newm);   // 0 for masked/invalid
            l_run += p;                               // per-lane partial (q4 rows)
            av.x = fmaf(p, vv[mt & 1][rr].x, av.x);
            av.y = fmaf(p, vv[mt & 1][rr].y, av.y);
        }
    }

    // ---- cross-q4 reductions (within wave; waves hold identical softmax) ----
#pragma unroll
    for (int nt = 0; nt < 4; ++nt) {
        poolAcc[nt] += __shfl_xor(poolAcc[nt], 16, 64);
        poolAcc[nt] += __shfl_xor(poolAcc[nt], 32, 64);
    }
    l_run += __shfl_xor(l_run, 16, 64);
    l_run += __shfl_xor(l_run, 32, 64);
    av.x  += __shfl_xor(av.x, 16, 64);
    av.x  += __shfl_xor(av.x, 32, 64);
    av.y  += __shfl_xor(av.y, 16, 64);
    av.y  += __shfl_xor(av.y, 32, 64);

    float cnt = 0.f;
    for (int i = lane; i < Mm; i += 64) cnt += maskS[i];
#pragma unroll
    for (int off = 32; off > 0; off >>= 1) cnt += __shfl_xor(cnt, off, 64);

    if (w == 0 && lane < 16) {
#pragma unroll
        for (int nt = 0; nt < 4; ++nt)
            poolS[nt * 16 + lane] = poolAcc[nt] / cnt;
    }
    __syncthreads();

    const float v2x = av.x / l_run;
    const float v2y = av.y / l_run;

    // ---- channel gate: lane owns cols {colOff, colOff+1}; e split by q4 ----
    float a0 = 0.f, a1 = 0.f;
#pragma unroll
    for (int i = 0; i < 16; ++i) {
        const int e = q4 * 16 + i;
        const float pe = poolS[e];
        const float2 wc = *(const float2*)(W_channel + (size_t)e * DVv + colOff);
        a0 = fmaf(pe, wc.x, a0);
        a1 = fmaf(pe, wc.y, a1);
    }
    a0 += __shfl_xor(a0, 16, 64); a0 += __shfl_xor(a0, 32, 64);
    a1 += __shfl_xor(a1, 16, 64); a1 += __shfl_xor(a1, 32, 64);

    if (q4 == 0) {
        const float2 bc = *(const float2*)(b_channel + colOff);
        const float ch0 = 1.f / (1.f + __expf(-(a0 + bc.x)));
        const float ch1 = 1.f / (1.f + __expf(-(a1 + bc.y)));
        const float2 v1 = *(const float2*)(value1 + (size_t)bh * DVv + colOff);
        float2 o;
        o.x = v1.x * v2x * ch0;
        o.y = v1.y * v2y * ch1;
        *(float2*)(out + (size_t)bh * DVv + colOff) = o;
    }
}

extern "C" void kernel_launch(void* const* d_in, const int* in_sizes, int n_in,
                              void* d_out, int out_size, void* d_ws, size_t ws_size,
                              hipStream_t stream) {
    const float* query     = (const float*)d_in[0];
    const float* key       = (const float*)d_in[1];
    const float* att_mask  = (const float*)d_in[2];
    const float* value1    = (const float*)d_in[3];
    const float* value2    = (const float*)d_in[4];
    const float* W_basic   = (const float*)d_in[5];
    const float* b_basic   = (const float*)d_in[6];
    const float* W_spatial = (const float*)d_in[7];
    const float* b_spatial = (const float*)d_in[8];
    const float* W_channel = (const float*)d_in[9];
    const float* b_channel = (const float*)d_in[10];
    float* out = (float*)d_out;

    scatt_fused<<<NBH, 256, 0, stream>>>(query, key, att_mask, value1, value2,
                                         W_basic, b_basic, W_spatial, b_spatial,
                                         W_channel, b_channel, out);
}

// Round 9
// 255.070 us; speedup vs baseline: 1.7290x; 1.7290x over previous
//
#include <hip/hip_runtime.h>
#include <cstddef>

// Problem shapes (fixed by reference)
#define NBH  1024   // B*H
#define Mm   196
#define Dd   128
#define MIDe 64
#define DVv  128
#define WQLD 136    // WqT row length in shorts (128 + 8 pad -> 272 B rows)

typedef __attribute__((ext_vector_type(8))) short bf16x8;  // 8 bf16 in 4 VGPRs
typedef __attribute__((ext_vector_type(4))) float f32x4;   // MFMA C/D frag

__device__ __forceinline__ short f2bf(float x) {           // fp32 -> bf16 RNE
    union { float f; unsigned u; } v; v.f = x;
    return (short)((v.u + 0x7FFFu + ((v.u >> 16) & 1u)) >> 16);
}

// async 16B global->LDS DMA: no data VGPRs, tracked by vmcnt.
// LDS dest is wave-uniform base + lane*16 (HW); global src is per-lane.
__device__ __forceinline__ void gl_lds16(const void* g, void* l) {
    __builtin_amdgcn_global_load_lds(
        (const __attribute__((address_space(1))) unsigned int*)g,
        (__attribute__((address_space(3))) unsigned int*)l, 16, 0, 0);
}

// Round-9: round-8's DMA-staging architecture with its two codegen poisons
// removed. R8 counters: WRITE 354 MB / FETCH 278 MB scratch traffic, VGPR=64
// -> (a) the 13-iter loop didn't fully unroll, so vv[(mt+1)&1] was runtime-
// indexed -> localMem (rule: runtime-indexed arrays go to scratch); (b)
// launch_bounds(256,4) spill-chases 8 waves/EU (R3/R4/R8), while (256,2)
// has never spilled (R6/R7: VGPR 100-120, WRITE 0.5 MB). Fixes:
//  - NAMED double-buffers vvA/vvB + macro tile body with LITERAL parity:
//    every array index is a compile-time constant -> registers, guaranteed.
//  - launch_bounds(256,2). Occupancy is LDS-capped at 4 blocks/CU anyway
//    (35.8 KB/block); demand ~80 regs <= 128 keeps 16 waves/CU schedulable.
// Architecture (unchanged from R8): key tiles DMA'd into a double-buffered
// LDS tile stored TRANSPOSED in 16B cells [d4][row] via per-lane source
// addressing (frag ds_read_b128 conflict-free); all 4 waves compute each
// tile redundantly (16 MFMA - cheap) which deletes the cross-wave softmax
// merge; each wave owns 32 value2 columns (4 float2 regs/tile, dbuf'd);
// in-loop sync = counted s_waitcnt vmcnt(4) + raw s_barrier.
__global__ __launch_bounds__(256, 2)
void scatt_fused(const float* __restrict__ query,
                 const float* __restrict__ key,
                 const float* __restrict__ att_mask,
                 const float* __restrict__ value1,
                 const float* __restrict__ value2,
                 const float* __restrict__ W_basic,
                 const float* __restrict__ b_basic,
                 const float* __restrict__ W_spatial,
                 const float* __restrict__ b_spatial,
                 const float* __restrict__ W_channel,
                 const float* __restrict__ b_channel,
                 float* __restrict__ out)
{
    __shared__ float4 kb[2][32][16];    // 16 KB: key tile dbuf, cell [d4][row]
    __shared__ short  wqT[MIDe][WQLD];  // 17.4 KB bf16 Wq^T[e][d]
    __shared__ float  qS[Dd];
    __shared__ float  maskS[Mm];
    __shared__ float  poolS[MIDe];

    const int t    = threadIdx.x;
    const int lane = t & 63;
    const int w    = t >> 6;            // wave id 0..3
    const int ln15 = lane & 15;
    const int q4   = lane >> 4;         // quad id 0..3
    const int bh   = blockIdx.x;
    const int b    = bh >> 3;

    const char*  keyC  = (const char*)(key + (size_t)bh * Mm * Dd);
    const float* val2B = value2   + (size_t)bh * Mm * DVv;
    const float* qB    = query    + (size_t)bh * Dd;
    const float* maskB = att_mask + (size_t)b  * Mm;

    // Staging source offsets (transpose done on the per-lane SOURCE side):
    // dest 16B-cell index = w*128 + j*64 + lane; d4 = cell>>4, row = cell&15;
    // src byte within tile = row*512 + d4*16. Tail tile clamps row to 3
    // (rows 196..207 read row-195 data; their logits are masked -> p==0).
    // Scalars (not arrays) so no address-taken locals.
    const int cell0 = w * 128 + lane;
    const int cell1 = cell0 + 64;
    const int r0 = cell0 & 15, d40 = cell0 >> 4;
    const int r1 = cell1 & 15, d41 = cell1 >> 4;
    const int so0  = r0 * 512 + d40 * 16;
    const int so1  = r1 * 512 + d41 * 16;
    const int soT0 = (r0 < 4 ? r0 : 3) * 512 + d40 * 16;
    const int soT1 = (r1 < 4 ? r1 : 3) * 512 + d41 * 16;
    const int colOff = w * 32 + 2 * ln15;   // v2 column pair this lane owns

    // ---- issue stage(0) + v2(0) immediately (fly under the prologue)
    gl_lds16(keyC + so0, (char*)kb + w * 2048);
    gl_lds16(keyC + so1, (char*)kb + w * 2048 + 1024);
    float2 vvA[4], vvB[4];
#pragma unroll
    for (int rr = 0; rr < 4; ++rr)
        vvA[rr] = *(const float2*)(val2B + (size_t)(q4 * 4 + rr) * DVv + colOff);

    // ---- Prologue: stage q + mask; build WqT cooperatively ----
    if (t < 32) ((float4*)qS)[t] = ((const float4*)qB)[t];
    for (int i = t; i < Mm; i += 256) maskS[i] = maskB[i];
    __syncthreads();
    {
        const int e0 = lane;            // e column this thread fills
        const int d0 = w * 32;
#pragma unroll
        for (int c = 0; c < 4; ++c) {
            short pk[8];
#pragma unroll
            for (int j = 0; j < 8; ++j) {
                const int d = d0 + c * 8 + j;
                pk[j] = f2bf(qS[d] * W_basic[d * MIDe + e0]);
            }
            *(bf16x8*)&wqT[e0][d0 + c * 8] = *(bf16x8*)pk;
        }
    }
    __syncthreads();   // drains vmcnt too -> stage(0)/v2(0) complete here

    float bbv[4], wspv[4];
#pragma unroll
    for (int nt = 0; nt < 4; ++nt) {
        bbv[nt]  = b_basic[nt * 16 + ln15];
        wspv[nt] = W_spatial[nt * 16 + ln15];
    }
    const float bsp = b_spatial[0];

    float poolAcc[4] = {0.f, 0.f, 0.f, 0.f};
    float m_run = -3.0e38f, l_run = 0.f;
    float2 av = make_float2(0.f, 0.f);

// One tile step. MT may be runtime; PAR/PF are LITERALS; VCUR/VNXT are
// NAMED arrays -> all register-resident. PF: 0=none, 1=normal, 2=tail.
// vmcnt(4): at entry in-flight = stage(MT)[2, oldest] + vv(MT)[4]; drains
// exactly the 2 stage DMAs. Compiler adds its own counted wait for VCUR.
#define TILE_STEP(MT, PAR, VCUR, VNXT, PF)                                   \
    do {                                                                     \
        asm volatile("s_waitcnt vmcnt(4)" ::: "memory");                     \
        __builtin_amdgcn_s_barrier();                                        \
        __builtin_amdgcn_sched_barrier(0);                                   \
        if (PF) {                                                            \
            char* db = (char*)kb + ((PAR) ^ 1) * 8192;                       \
            const char* sb = keyC + (size_t)((MT) + 1) * 8192;               \
            if ((PF) == 1) {                                                 \
                gl_lds16(sb + so0, db + w * 2048);                           \
                gl_lds16(sb + so1, db + w * 2048 + 1024);                    \
            } else {                                                         \
                gl_lds16(sb + soT0, db + w * 2048);                          \
                gl_lds16(sb + soT1, db + w * 2048 + 1024);                   \
            }                                                                \
            __builtin_amdgcn_sched_barrier(0);                               \
            _Pragma("unroll")                                                \
            for (int rr = 0; rr < 4; ++rr) {                                 \
                int vrow = ((MT) + 1) * 16 + q4 * 4 + rr;                    \
                if ((PF) == 2) vrow = vrow < Mm ? vrow : (Mm - 1);           \
                VNXT[rr] =                                                   \
                    *(const float2*)(val2B + (size_t)vrow * DVv + colOff);   \
            }                                                                \
        }                                                                    \
        const char* kbB = (const char*)kb + (PAR) * 8192;                    \
        f32x4 acc[4] = {f32x4{0,0,0,0}, f32x4{0,0,0,0},                      \
                        f32x4{0,0,0,0}, f32x4{0,0,0,0}};                     \
        _Pragma("unroll")                                                    \
        for (int ks = 0; ks < 4; ++ks) {                                     \
            const int d4 = ks * 8 + q4 * 2;                                  \
            const float4 f0 = *(const float4*)(kbB + d4 * 256 + ln15 * 16);  \
            const float4 f1 =                                                \
                *(const float4*)(kbB + d4 * 256 + 256 + ln15 * 16);          \
            const bf16x8 af = { f2bf(f0.x), f2bf(f0.y), f2bf(f0.z),          \
                                f2bf(f0.w), f2bf(f1.x), f2bf(f1.y),          \
                                f2bf(f1.z), f2bf(f1.w) };                    \
            _Pragma("unroll")                                                \
            for (int nt = 0; nt < 4; ++nt) {                                 \
                const bf16x8 bk =                                            \
                    *(const bf16x8*)&wqT[nt * 16 + ln15][ks * 32 + q4 * 8];  \
                acc[nt] = __builtin_amdgcn_mfma_f32_16x16x32_bf16(           \
                              af, bk, acc[nt], 0, 0, 0);                     \
            }                                                                \
        }                                                                    \
        float sR[4];                                                         \
        _Pragma("unroll")                                                    \
        for (int rr = 0; rr < 4; ++rr) {                                     \
            const int m = (MT) * 16 + q4 * 4 + rr;                           \
            const bool valid = m < Mm;                                       \
            const float msk = valid ? maskS[m] : 0.f;                        \
            float srow = 0.f;                                                \
            _Pragma("unroll")                                                \
            for (int nt = 0; nt < 4; ++nt) {                                 \
                float hv = acc[nt][rr] + bbv[nt];                            \
                hv = hv > 0.f ? hv : 0.f;                                    \
                poolAcc[nt] = fmaf(hv, msk, poolAcc[nt]);                    \
                srow = fmaf(hv, wspv[nt], srow);                             \
            }                                                                \
            srow += __shfl_xor(srow, 1, 64);                                 \
            srow += __shfl_xor(srow, 2, 64);                                 \
            srow += __shfl_xor(srow, 4, 64);                                 \
            srow += __shfl_xor(srow, 8, 64);                                 \
            sR[rr] = valid ? (msk == 0.f ? -1.0e9f : srow + bsp) : -3.0e38f; \
        }                                                                    \
        float tm = fmaxf(fmaxf(sR[0], sR[1]), fmaxf(sR[2], sR[3]));          \
        tm = fmaxf(tm, __shfl_xor(tm, 16, 64));                              \
        tm = fmaxf(tm, __shfl_xor(tm, 32, 64));                              \
        const float newm = fmaxf(m_run, tm);                                 \
        const float sc = __expf(m_run - newm);                               \
        m_run = newm;                                                        \
        l_run *= sc; av.x *= sc; av.y *= sc;                                 \
        _Pragma("unroll")                                                    \
        for (int rr = 0; rr < 4; ++rr) {                                     \
            const float p = __expf(sR[rr] - newm);                           \
            l_run += p;                                                      \
            av.x = fmaf(p, VCUR[rr].x, av.x);                                \
            av.y = fmaf(p, VCUR[rr].y, av.y);                                \
        }                                                                    \
    } while (0)

    // tiles 0..9 in pairs, then 10, 11 (prefetches clamped tail), then 12
    for (int mtp = 0; mtp < 5; ++mtp) {
        const int mt0 = 2 * mtp;
        TILE_STEP(mt0,     0, vvA, vvB, 1);
        TILE_STEP(mt0 + 1, 1, vvB, vvA, 1);
    }
    TILE_STEP(10, 0, vvA, vvB, 1);
    TILE_STEP(11, 1, vvB, vvA, 2);
    TILE_STEP(12, 0, vvA, vvB, 0);
#undef TILE_STEP

    // ---- cross-q4 reductions (within wave; waves hold identical softmax) ----
#pragma unroll
    for (int nt = 0; nt < 4; ++nt) {
        poolAcc[nt] += __shfl_xor(poolAcc[nt], 16, 64);
        poolAcc[nt] += __shfl_xor(poolAcc[nt], 32, 64);
    }
    l_run += __shfl_xor(l_run, 16, 64);
    l_run += __shfl_xor(l_run, 32, 64);
    av.x  += __shfl_xor(av.x, 16, 64);
    av.x  += __shfl_xor(av.x, 32, 64);
    av.y  += __shfl_xor(av.y, 16, 64);
    av.y  += __shfl_xor(av.y, 32, 64);

    float cnt = 0.f;
    for (int i = lane; i < Mm; i += 64) cnt += maskS[i];
#pragma unroll
    for (int off = 32; off > 0; off >>= 1) cnt += __shfl_xor(cnt, off, 64);

    if (w == 0 && lane < 16) {
#pragma unroll
        for (int nt = 0; nt < 4; ++nt)
            poolS[nt * 16 + lane] = poolAcc[nt] / cnt;
    }
    __syncthreads();

    const float v2x = av.x / l_run;
    const float v2y = av.y / l_run;

    // ---- channel gate: lane owns cols {colOff, colOff+1}; e split by q4 ----
    float a0 = 0.f, a1 = 0.f;
#pragma unroll
    for (int i = 0; i < 16; ++i) {
        const int e = q4 * 16 + i;
        const float pe = poolS[e];
        const float2 wc = *(const float2*)(W_channel + (size_t)e * DVv + colOff);
        a0 = fmaf(pe, wc.x, a0);
        a1 = fmaf(pe, wc.y, a1);
    }
    a0 += __shfl_xor(a0, 16, 64); a0 += __shfl_xor(a0, 32, 64);
    a1 += __shfl_xor(a1, 16, 64); a1 += __shfl_xor(a1, 32, 64);

    if (q4 == 0) {
        const float2 bc = *(const float2*)(b_channel + colOff);
        const float ch0 = 1.f / (1.f + __expf(-(a0 + bc.x)));
        const float ch1 = 1.f / (1.f + __expf(-(a1 + bc.y)));
        const float2 v1 = *(const float2*)(value1 + (size_t)bh * DVv + colOff);
        float2 o;
        o.x = v1.x * v2x * ch0;
        o.y = v1.y * v2y * ch1;
        *(float2*)(out + (size_t)bh * DVv + colOff) = o;
    }
}

extern "C" void kernel_launch(void* const* d_in, const int* in_sizes, int n_in,
                              void* d_out, int out_size, void* d_ws, size_t ws_size,
                              hipStream_t stream) {
    const float* query     = (const float*)d_in[0];
    const float* key       = (const float*)d_in[1];
    const float* att_mask  = (const float*)d_in[2];
    const float* value1    = (const float*)d_in[3];
    const float* value2    = (const float*)d_in[4];
    const float* W_basic   = (const float*)d_in[5];
    const float* b_basic   = (const float*)d_in[6];
    const float* W_spatial = (const float*)d_in[7];
    const float* b_spatial = (const float*)d_in[8];
    const float* W_channel = (const float*)d_in[9];
    const float* b_channel = (const float*)d_in[10];
    float* out = (float*)d_out;

    scatt_fused<<<NBH, 256, 0, stream>>>(query, key, att_mask, value1, value2,
                                         W_basic, b_basic, W_spatial, b_spatial,
                                         W_channel, b_channel, out);
}

// Round 10
// 247.544 us; speedup vs baseline: 1.7816x; 1.0304x over previous
//
#include <hip/hip_runtime.h>
#include <cstddef>

// Problem shapes (fixed by reference)
#define NBH  1024   // B*H
#define Mm   196
#define Dd   128
#define MIDe 64
#define DVv  128
#define WQLD 136    // WqT row length in shorts (128 + 8 pad -> 272 B rows)

typedef __attribute__((ext_vector_type(8))) short bf16x8;  // 8 bf16 in 4 VGPRs
typedef __attribute__((ext_vector_type(4))) float f32x4;   // MFMA C/D frag

__device__ __forceinline__ short f2bf(float x) {           // fp32 -> bf16 RNE
    union { float f; unsigned u; } v; v.f = x;
    return (short)((v.u + 0x7FFFu + ((v.u >> 16) & 1u)) >> 16);
}

// async 16B global->LDS DMA: no data VGPRs, tracked by vmcnt.
__device__ __forceinline__ void gl_lds16(const void* g, void* l) {
    __builtin_amdgcn_global_load_lds(
        (const __attribute__((address_space(1))) unsigned int*)g,
        (__attribute__((address_space(3))) unsigned int*)l, 16, 0, 0);
}

// Round-10: R9 (DMA staging, no spills) was still 1-tile-deep: per-tile time
// collapsed to the load round-trip (18.6K cy/tile, only ~4K VALU), since
// stage(t+1) issued at t is waited at t+1 and compute << latency under
// full-grid congestion. Fix: DEPTH-2 prefetch, 3-buffer LDS ring.
//   tile t body: vmcnt(10) [drains stage(t) exactly; 10 newer stay in
//   flight] -> s_barrier -> ds_read buf(t%3) + build af -> issue
//   stage(t+2) into buf((t+2)%3) + vv(t+2) -> MFMA/epilogue/softmax.
// Ring-safety: buf((t+2)%3) was last read at tile t-1; every wave passed
// barrier(t) before any stage(t+2) issues -> no race. Ring parities and vv
// buffers are macro LITERALS (rule: runtime-indexed arrays -> scratch).
// launch_bounds(256,2): the only no-spill config this session. LDS 43.5 KB
// -> 3 blocks/CU.
__global__ __launch_bounds__(256, 2)
void scatt_fused(const float* __restrict__ query,
                 const float* __restrict__ key,
                 const float* __restrict__ att_mask,
                 const float* __restrict__ value1,
                 const float* __restrict__ value2,
                 const float* __restrict__ W_basic,
                 const float* __restrict__ b_basic,
                 const float* __restrict__ W_spatial,
                 const float* __restrict__ b_spatial,
                 const float* __restrict__ W_channel,
                 const float* __restrict__ b_channel,
                 float* __restrict__ out)
{
    __shared__ float4 kb[3][32][16];    // 24 KB: key tile ring, cell [d4][row]
    __shared__ short  wqT[MIDe][WQLD];  // 17.4 KB bf16 Wq^T[e][d]
    __shared__ float  qS[Dd];
    __shared__ float  maskS[Mm];
    __shared__ float  poolS[MIDe];

    const int t    = threadIdx.x;
    const int lane = t & 63;
    const int w    = t >> 6;            // wave id 0..3
    const int ln15 = lane & 15;
    const int q4   = lane >> 4;         // quad id 0..3
    const int bh   = blockIdx.x;
    const int b    = bh >> 3;

    const char*  keyC  = (const char*)(key + (size_t)bh * Mm * Dd);
    const float* val2B = value2   + (size_t)bh * Mm * DVv;
    const float* qB    = query    + (size_t)bh * Dd;
    const float* maskB = att_mask + (size_t)b  * Mm;

    // Staging source offsets (transpose on the per-lane SOURCE side):
    // dest cell = w*128 + j*64 + lane; d4 = cell>>4, row = cell&15;
    // src byte = row*512 + d4*16. Tail tile clamps row to 3 (clamped rows'
    // logits are masked -> p==0, inert).
    const int cell0 = w * 128 + lane;
    const int cell1 = cell0 + 64;
    const int r0 = cell0 & 15, d40 = cell0 >> 4;
    const int r1 = cell1 & 15, d41 = cell1 >> 4;
    const int so0  = r0 * 512 + d40 * 16;
    const int so1  = r1 * 512 + d41 * 16;
    const int soT0 = (r0 < 4 ? r0 : 3) * 512 + d40 * 16;
    const int soT1 = (r1 < 4 ? r1 : 3) * 512 + d41 * 16;
    const int colOff = w * 32 + 2 * ln15;   // v2 column pair this lane owns

    // ---- stage(0) + vv(0) fly under the prologue
    gl_lds16(keyC + so0, (char*)kb + w * 2048);
    gl_lds16(keyC + so1, (char*)kb + w * 2048 + 1024);
    float2 vvA[4], vvB[4], vvC[4];
#pragma unroll
    for (int rr = 0; rr < 4; ++rr)
        vvA[rr] = *(const float2*)(val2B + (size_t)(q4 * 4 + rr) * DVv + colOff);

    // ---- Prologue: stage q + mask; build WqT cooperatively ----
    if (t < 32) ((float4*)qS)[t] = ((const float4*)qB)[t];
    for (int i = t; i < Mm; i += 256) maskS[i] = maskB[i];
    __syncthreads();
    {
        const int e0 = lane;
        const int d0 = w * 32;
#pragma unroll
        for (int c = 0; c < 4; ++c) {
            short pk[8];
#pragma unroll
            for (int j = 0; j < 8; ++j) {
                const int d = d0 + c * 8 + j;
                pk[j] = f2bf(qS[d] * W_basic[d * MIDe + e0]);
            }
            *(bf16x8*)&wqT[e0][d0 + c * 8] = *(bf16x8*)pk;
        }
    }
    __syncthreads();   // drains vmcnt -> stage(0)/vv(0) complete

    // stage(1) + vv(1): issued after the drain so they stay in flight
    gl_lds16(keyC + 8192 + so0, (char*)kb + 8192 + w * 2048);
    gl_lds16(keyC + 8192 + so1, (char*)kb + 8192 + w * 2048 + 1024);
#pragma unroll
    for (int rr = 0; rr < 4; ++rr)
        vvB[rr] = *(const float2*)(val2B + (size_t)(16 + q4 * 4 + rr) * DVv + colOff);

    float bbv[4], wspv[4];
#pragma unroll
    for (int nt = 0; nt < 4; ++nt) {
        bbv[nt]  = b_basic[nt * 16 + ln15];
        wspv[nt] = W_spatial[nt * 16 + ln15];
    }
    const float bsp = b_spatial[0];

    float poolAcc[4] = {0.f, 0.f, 0.f, 0.f};
    float m_run = -3.0e38f, l_run = 0.f;
    float2 av = make_float2(0.f, 0.f);

// One tile step. MT runtime; PAR/PNX literal ring slots (PNX=(PAR+2)%3);
// VCUR/VN2 named reg arrays (literal); PF: 1=prefetch MT+2, 2=tail-clamped
// prefetch, 0=none. WAITASM: "s_waitcnt vmcnt(10)" steady / "(4)" at MT=12.
// Order: wait -> barrier -> ds_read+af -> issue prefetch -> MFMA/epilogue.
#define TILE_STEP(MT, PAR, PNX, VCUR, VN2, PF, WAITASM)                      \
    do {                                                                     \
        asm volatile(WAITASM ::: "memory");                                  \
        __builtin_amdgcn_s_barrier();                                        \
        __builtin_amdgcn_sched_barrier(0);                                   \
        const char* kbB = (const char*)kb + (PAR) * 8192;                    \
        bf16x8 af[4];                                                        \
        _Pragma("unroll")                                                    \
        for (int ks = 0; ks < 4; ++ks) {                                     \
            const int d4 = ks * 8 + q4 * 2;                                  \
            const float4 f0 = *(const float4*)(kbB + d4 * 256 + ln15 * 16);  \
            const float4 f1 =                                                \
                *(const float4*)(kbB + d4 * 256 + 256 + ln15 * 16);          \
            af[ks] = bf16x8{ f2bf(f0.x), f2bf(f0.y), f2bf(f0.z), f2bf(f0.w), \
                             f2bf(f1.x), f2bf(f1.y), f2bf(f1.z), f2bf(f1.w)};\
        }                                                                    \
        __builtin_amdgcn_sched_barrier(0);                                   \
        if (PF) {                                                            \
            char* db = (char*)kb + (PNX) * 8192;                             \
            const char* sb = keyC + (size_t)((MT) + 2) * 8192;               \
            if ((PF) == 1) {                                                 \
                gl_lds16(sb + so0, db + w * 2048);                           \
                gl_lds16(sb + so1, db + w * 2048 + 1024);                    \
            } else {                                                         \
                gl_lds16(sb + soT0, db + w * 2048);                          \
                gl_lds16(sb + soT1, db + w * 2048 + 1024);                   \
            }                                                                \
            _Pragma("unroll")                                                \
            for (int rr = 0; rr < 4; ++rr) {                                 \
                int vrow = ((MT) + 2) * 16 + q4 * 4 + rr;                    \
                if ((PF) == 2) vrow = vrow < Mm ? vrow : (Mm - 1);           \
                VN2[rr] =                                                    \
                    *(const float2*)(val2B + (size_t)vrow * DVv + colOff);   \
            }                                                                \
            __builtin_amdgcn_sched_barrier(0);                               \
        }                                                                    \
        f32x4 acc[4] = {f32x4{0,0,0,0}, f32x4{0,0,0,0},                      \
                        f32x4{0,0,0,0}, f32x4{0,0,0,0}};                     \
        _Pragma("unroll")                                                    \
        for (int ks = 0; ks < 4; ++ks) {                                     \
            _Pragma("unroll")                                                \
            for (int nt = 0; nt < 4; ++nt) {                                 \
                const bf16x8 bk =                                            \
                    *(const bf16x8*)&wqT[nt * 16 + ln15][ks * 32 + q4 * 8];  \
                acc[nt] = __builtin_amdgcn_mfma_f32_16x16x32_bf16(           \
                              af[ks], bk, acc[nt], 0, 0, 0);                 \
            }                                                                \
        }                                                                    \
        float sR[4];                                                         \
        _Pragma("unroll")                                                    \
        for (int rr = 0; rr < 4; ++rr) {                                     \
            const int m = (MT) * 16 + q4 * 4 + rr;                           \
            const bool valid = m < Mm;                                       \
            const float msk = valid ? maskS[m] : 0.f;                        \
            float srow = 0.f;                                                \
            _Pragma("unroll")                                                \
            for (int nt = 0; nt < 4; ++nt) {                                 \
                float hv = acc[nt][rr] + bbv[nt];                            \
                hv = hv > 0.f ? hv : 0.f;                                    \
                poolAcc[nt] = fmaf(hv, msk, poolAcc[nt]);                    \
                srow = fmaf(hv, wspv[nt], srow);                             \
            }                                                                \
            srow += __shfl_xor(srow, 1, 64);                                 \
            srow += __shfl_xor(srow, 2, 64);                                 \
            srow += __shfl_xor(srow, 4, 64);                                 \
            srow += __shfl_xor(srow, 8, 64);                                 \
            sR[rr] = valid ? (msk == 0.f ? -1.0e9f : srow + bsp) : -3.0e38f; \
        }                                                                    \
        float tm = fmaxf(fmaxf(sR[0], sR[1]), fmaxf(sR[2], sR[3]));          \
        tm = fmaxf(tm, __shfl_xor(tm, 16, 64));                              \
        tm = fmaxf(tm, __shfl_xor(tm, 32, 64));                              \
        const float newm = fmaxf(m_run, tm);                                 \
        const float sc = __expf(m_run - newm);                               \
        m_run = newm;                                                        \
        l_run *= sc; av.x *= sc; av.y *= sc;                                 \
        _Pragma("unroll")                                                    \
        for (int rr = 0; rr < 4; ++rr) {                                     \
            const float p = __expf(sR[rr] - newm);                           \
            l_run += p;                                                      \
            av.x = fmaf(p, VCUR[rr].x, av.x);                                \
            av.y = fmaf(p, VCUR[rr].y, av.y);                                \
        }                                                                    \
    } while (0)

    // tiles 0..8 (3 ring periods), then 9,10 (10 prefetches clamped tail 12),
    // then 11, 12 (no prefetch)
    for (int g = 0; g < 3; ++g) {
        const int t0 = g * 3;
        TILE_STEP(t0,     0, 2, vvA, vvC, 1, "s_waitcnt vmcnt(10)");
        TILE_STEP(t0 + 1, 1, 0, vvB, vvA, 1, "s_waitcnt vmcnt(10)");
        TILE_STEP(t0 + 2, 2, 1, vvC, vvB, 1, "s_waitcnt vmcnt(10)");
    }
    TILE_STEP(9,  0, 2, vvA, vvC, 1, "s_waitcnt vmcnt(10)");
    TILE_STEP(10, 1, 0, vvB, vvA, 2, "s_waitcnt vmcnt(10)");
    TILE_STEP(11, 2, 1, vvC, vvB, 0, "s_waitcnt vmcnt(10)");
    TILE_STEP(12, 0, 2, vvA, vvC, 0, "s_waitcnt vmcnt(4)");
#undef TILE_STEP

    // ---- cross-q4 reductions (within wave; waves hold identical softmax) ----
#pragma unroll
    for (int nt = 0; nt < 4; ++nt) {
        poolAcc[nt] += __shfl_xor(poolAcc[nt], 16, 64);
        poolAcc[nt] += __shfl_xor(poolAcc[nt], 32, 64);
    }
    l_run += __shfl_xor(l_run, 16, 64);
    l_run += __shfl_xor(l_run, 32, 64);
    av.x  += __shfl_xor(av.x, 16, 64);
    av.x  += __shfl_xor(av.x, 32, 64);
    av.y  += __shfl_xor(av.y, 16, 64);
    av.y  += __shfl_xor(av.y, 32, 64);

    float cnt = 0.f;
    for (int i = lane; i < Mm; i += 64) cnt += maskS[i];
#pragma unroll
    for (int off = 32; off > 0; off >>= 1) cnt += __shfl_xor(cnt, off, 64);

    if (w == 0 && lane < 16) {
#pragma unroll
        for (int nt = 0; nt < 4; ++nt)
            poolS[nt * 16 + lane] = poolAcc[nt] / cnt;
    }
    __syncthreads();

    const float v2x = av.x / l_run;
    const float v2y = av.y / l_run;

    // ---- channel gate: lane owns cols {colOff, colOff+1}; e split by q4 ----
    float a0 = 0.f, a1 = 0.f;
#pragma unroll
    for (int i = 0; i < 16; ++i) {
        const int e = q4 * 16 + i;
        const float pe = poolS[e];
        const float2 wc = *(const float2*)(W_channel + (size_t)e * DVv + colOff);
        a0 = fmaf(pe, wc.x, a0);
        a1 = fmaf(pe, wc.y, a1);
    }
    a0 += __shfl_xor(a0, 16, 64); a0 += __shfl_xor(a0, 32, 64);
    a1 += __shfl_xor(a1, 16, 64); a1 += __shfl_xor(a1, 32, 64);

    if (q4 == 0) {
        const float2 bc = *(const float2*)(b_channel + colOff);
        const float ch0 = 1.f / (1.f + __expf(-(a0 + bc.x)));
        const float ch1 = 1.f / (1.f + __expf(-(a1 + bc.y)));
        const float2 v1 = *(const float2*)(value1 + (size_t)bh * DVv + colOff);
        float2 o;
        o.x = v1.x * v2x * ch0;
        o.y = v1.y * v2y * ch1;
        *(float2*)(out + (size_t)bh * DVv + colOff) = o;
    }
}

extern "C" void kernel_launch(void* const* d_in, const int* in_sizes, int n_in,
                              void* d_out, int out_size, void* d_ws, size_t ws_size,
                              hipStream_t stream) {
    const float* query     = (const float*)d_in[0];
    const float* key       = (const float*)d_in[1];
    const float* att_mask  = (const float*)d_in[2];
    const float* value1    = (const float*)d_in[3];
    const float* value2    = (const float*)d_in[4];
    const float* W_basic   = (const float*)d_in[5];
    const float* b_basic   = (const float*)d_in[6];
    const float* W_spatial = (const float*)d_in[7];
    const float* b_spatial = (const float*)d_in[8];
    const float* W_channel = (const float*)d_in[9];
    const float* b_channel = (const float*)d_in[10];
    float* out = (float*)d_out;

    scatt_fused<<<NBH, 256, 0, stream>>>(query, key, att_mask, value1, value2,
                                         W_basic, b_basic, W_spatial, b_spatial,
                                         W_channel, b_channel, out);
}